// Round 17
// baseline (303.734 us; speedup 1.0000x reference)
//
#include <hip/hip_runtime.h>

#define NN 100000
#define NE 800000
#define NRG 256       // dst ranges per relation
#define SPAN 392      // nodes per range (256*392 = 100352 >= NN)
#define CAP 4096      // capacity per (relation,range) bin; mean 3125, +17 sigma
#define NBIN (9 * NRG)
#define ACH 8192      // passA edges per block (runs avg 32 -> 128B write segments)
#define ABD 512       // passA block size (8 waves; 43KB LDS -> 3 blocks/CU)

typedef _Float16 f16;
typedef __attribute__((ext_vector_type(4))) _Float16 f16x4;
typedef __attribute__((ext_vector_type(8))) _Float16 f16x8;
typedef __attribute__((ext_vector_type(4))) float f32x4;
typedef __attribute__((ext_vector_type(2))) float f32x2;

#define NTL(p) __builtin_nontemporal_load(p)

struct EPtrs { const int* s[9]; const int* d[9]; };

// ---------------- prep: combined weights + cursor zero ----------------
__global__ __launch_bounds__(256) void prep_weights(
    const float* __restrict__ W0n, const float* __restrict__ W0r, const float* __restrict__ b0,
    const float* __restrict__ W1n, const float* __restrict__ W1r, const float* __restrict__ b1,
    const float* __restrict__ P1,  const float* __restrict__ pb1,
    const float* __restrict__ W2n, const float* __restrict__ W2r, const float* __restrict__ b2,
    const float* __restrict__ P2,  const float* __restrict__ pb2,
    float* __restrict__ wc0, float* __restrict__ bc0,
    float* __restrict__ wc1, float* __restrict__ bc1,
    f16*   __restrict__ b2frag, float* __restrict__ bc2,
    int*   __restrict__ cursor)
{
    int gtid = blockIdx.x * 256 + threadIdx.x;
    int gstr = gridDim.x * 256;

    for (int t = gtid; t < NBIN; t += gstr) cursor[t] = 0;

    for (int t = gtid; t < 18 * 16; t += gstr) {
        int row = t >> 4, col = t & 15;
        float v;
        if (row < 6)       v = W0n[row * 16 + col];
        else if (row < 12) v = W0n[96 + (row - 6) * 16 + col];
        else               v = W0r[(row - 12) * 16 + col] + W0r[96 + (row - 12) * 16 + col];
        wc0[t] = v;
    }
    for (int t = gtid; t < 16; t += gstr) bc0[t] = b0[t] + b0[16 + t];

    for (int t = gtid; t < 48 * 32; t += gstr) {
        int row = t >> 5, col = t & 31;
        float v;
        if (row < 16)      v = W1n[row * 32 + col];
        else if (row < 32) v = W1n[512 + (row - 16) * 32 + col];
        else { int rr = row - 32; v = W1r[rr * 32 + col] + W1r[512 + rr * 32 + col] + P1[rr * 32 + col]; }
        wc1[t] = v;
    }
    for (int t = gtid; t < 32; t += gstr) bc1[t] = b1[t] + b1[32 + t] + pb1[t];

    for (int t = gtid; t < 256 * 64; t += gstr) {
        int j = t & 7, lane = (t >> 3) & 63, ntk = t >> 9;
        int nt = ntk & 3, kt = ntk >> 2;
        int k = kt * 32 + (lane >> 4) * 8 + j;
        int n = nt * 16 + (lane & 15);
        float v;
        if (k < 224) v = W2n[k * 64 + n];
        else {
            int rr = k - 224;
            v = P2[rr * 64 + n];
            #pragma unroll
            for (int r = 0; r < 7; ++r) v += W2r[r * 2048 + rr * 64 + n];
        }
        b2frag[t] = (f16)v;
    }
    for (int t = gtid; t < 64; t += gstr) {
        float v = pb2[t];
        #pragma unroll
        for (int r = 0; r < 7; ++r) v += b2[r * 64 + t];
        bc2[t] = v;
    }
}

// ---------------- pass A: bucket edges by dst range (frozen, round-13) ----------------
__global__ __launch_bounds__(ABD) void passA(EPtrs ep, int* __restrict__ cursor,
                                             unsigned* __restrict__ binbuf)
{
    int r = blockIdx.y;
    int e0 = blockIdx.x * ACH;
    int cnt = min(ACH, NE - e0);
    int tid = threadIdx.x;
    __shared__ int h[NRG];
    __shared__ int bs[NRG];
    __shared__ int gb[NRG];
    __shared__ int wsumA[4];
    __shared__ unsigned pk[ACH];
    __shared__ unsigned char pkb[ACH];

    if (tid < NRG) h[tid] = 0;
    __syncthreads();

    const int* dp = ep.d[r];
    const int* sp = ep.s[r];
    unsigned wv[16];            // ACH/ABD == 16
    int rgk[16];
    int lrk[16];
    #pragma unroll
    for (int k = 0; k < 16; ++k) {
        int e = e0 + k * ABD + tid;
        rgk[k] = -1;
        if (e < NE) {
            int d = NTL(dp + e);
            int sv = NTL(sp + e);
            int g = d / SPAN;
            int l = d - g * SPAN;
            wv[k] = ((unsigned)l << 17) | (unsigned)sv;
            rgk[k] = g;
            lrk[k] = atomicAdd(&h[g], 1);
        }
    }
    __syncthreads();

    // scan of 256 counts in waves 0-3
    int vcnt = 0, incl = 0;
    int lane = tid & 63, wid = tid >> 6;
    if (tid < NRG) {
        vcnt = h[tid];
        incl = vcnt;
        #pragma unroll
        for (int ofs = 1; ofs < 64; ofs <<= 1) {
            int u = __shfl_up(incl, ofs, 64);
            if (lane >= ofs) incl += u;
        }
        if (lane == 63) wsumA[wid] = incl;
    }
    __syncthreads();
    if (tid == 0) {
        int a = wsumA[0], b = wsumA[1], c = wsumA[2];
        wsumA[0] = 0; wsumA[1] = a; wsumA[2] = a + b; wsumA[3] = a + b + c;
    }
    __syncthreads();
    if (tid < NRG) {
        int excl = incl - vcnt + wsumA[wid];
        bs[tid] = excl;
        gb[tid] = (vcnt > 0) ? atomicAdd(&cursor[r * NRG + tid], vcnt) : 0;
    }
    __syncthreads();

    #pragma unroll
    for (int k = 0; k < 16; ++k) {
        if (rgk[k] >= 0) {
            int p = bs[rgk[k]] + lrk[k];
            pk[p] = wv[k];
            pkb[p] = (unsigned char)rgk[k];
        }
    }
    __syncthreads();

    for (int i = tid; i < cnt; i += ABD) {
        int g = pkb[i];
        int pos = gb[g] + (i - bs[g]);
        if (pos < CAP)
            binbuf[((size_t)(r * NRG + g)) * CAP + pos] = pk[i];
    }
}

// ---------------- pass B: per-bin counting sort (hybrid, frozen) ----------------
__global__ __launch_bounds__(256) void passB(const unsigned* __restrict__ binbuf,
                                             const int* __restrict__ cursor,
                                             int* __restrict__ deg, int* __restrict__ off,
                                             int* __restrict__ eidx)
{
    int bin = blockIdx.x;
    int r = bin >> 8, rg = bin & (NRG - 1);
    int lo = rg * SPAN;
    int n_here = min(SPAN, NN - lo);
    int tid = threadIdx.x;
    __shared__ int h[SPAN];
    __shared__ int wsum[4];
    __shared__ int stage[CAP];

    int sz = min(cursor[bin], CAP);
    const unsigned* bp = binbuf + (size_t)bin * CAP;

    for (int i = tid; i < SPAN; i += 256) h[i] = 0;
    __syncthreads();

    unsigned wv[16];      // CAP/256 == 16: statically indexed (stays in VGPRs)
    int rk[16];
    #pragma unroll
    for (int k = 0; k < 16; ++k) {
        int e = tid + k * 256;
        if (e < sz) {
            unsigned w = NTL(bp + e);
            wv[k] = w;
            rk[k] = atomicAdd(&h[w >> 17], 1);
        }
    }
    __syncthreads();

    // scan counts -> row starts (in h); write deg / row-end off (2 per thread)
    int i0 = tid * 2;
    int dstash[2];
    int s = 0;
    #pragma unroll
    for (int k = 0; k < 2; ++k) {
        int i = i0 + k;
        int v = (i < SPAN) ? h[i] : 0;
        dstash[k] = v;
        s += v;
    }
    int lane = tid & 63, wid = tid >> 6;
    int incl = s;
    #pragma unroll
    for (int ofs = 1; ofs < 64; ofs <<= 1) {
        int u = __shfl_up(incl, ofs, 64);
        if (lane >= ofs) incl += u;
    }
    if (lane == 63) wsum[wid] = incl;
    __syncthreads();
    if (tid == 0) {
        int a = wsum[0], b = wsum[1], c = wsum[2];
        wsum[0] = 0; wsum[1] = a; wsum[2] = a + b; wsum[3] = a + b + c;
    }
    __syncthreads();
    int run = incl - s + wsum[wid];
    int base = bin * CAP;
    #pragma unroll
    for (int k = 0; k < 2; ++k) {
        int i = i0 + k;
        if (i < SPAN) {
            int v = dstash[k];
            h[i] = run;
            if (i < n_here) {
                deg[r * NN + lo + i] = v;
                off[r * NN + lo + i] = base + run + v;   // absolute row end
            }
            run += v;
        }
    }
    __syncthreads();

    // LDS scatter by rank, then coalesced copy out
    #pragma unroll
    for (int k = 0; k < 16; ++k) {
        int e = tid + k * 256;
        if (e < sz) {
            unsigned w = wv[k];
            stage[h[w >> 17] + rk[k]] = (int)(w & 0x1FFFF);
        }
    }
    __syncthreads();
    for (int i = tid; i < sz; i += 256) eidx[base + i] = stage[i];
}

// ---------------- layer 0: x(6) -> h0h(16 f16); 4 lanes/node (frozen) ----------------
__global__ __launch_bounds__(256) void t0f(const float* __restrict__ x,
                                           const int* __restrict__ deg, const int* __restrict__ off,
                                           const int* __restrict__ eidx,
                                           const float* __restrict__ wc0, const float* __restrict__ bc0,
                                           f16* __restrict__ h0h)
{
    __shared__ float sw[288 + 16];
    for (int t = threadIdx.x; t < 304; t += 256) sw[t] = (t < 288) ? wc0[t] : bc0[t - 288];
    __syncthreads();
    int t = blockIdx.x * 256 + threadIdx.x;
    int node = t >> 2;
    if (node >= NN) return;
    int l = t & 3;
    int r = l >> 1, p = l & 1;

    float m[6] = {0, 0, 0, 0, 0, 0};
    {
        int e1 = off[r * NN + node];
        int e0 = e1 - deg[r * NN + node];
        int e = e0 + p;                       // strided half: lanes p=0/1 interleave
        for (; e + 2 < e1; e += 4) {
            int sA = eidx[e], sB = eidx[e + 2];
            const float2* pA = reinterpret_cast<const float2*>(x + (size_t)sA * 6);
            const float2* pB = reinterpret_cast<const float2*>(x + (size_t)sB * 6);
            float2 a0 = pA[0], a1 = pA[1], a2 = pA[2];
            float2 b0 = pB[0], b1 = pB[1], b2 = pB[2];
            m[0] += a0.x + b0.x; m[1] += a0.y + b0.y;
            m[2] += a1.x + b1.x; m[3] += a1.y + b1.y;
            m[4] += a2.x + b2.x; m[5] += a2.y + b2.y;
        }
        if (e < e1) {
            int sA = eidx[e];
            const float2* pA = reinterpret_cast<const float2*>(x + (size_t)sA * 6);
            float2 a0 = pA[0], a1 = pA[1], a2 = pA[2];
            m[0] += a0.x; m[1] += a0.y; m[2] += a1.x; m[3] += a1.y; m[4] += a2.x; m[5] += a2.y;
        }
    }
    float mo[6];
    #pragma unroll
    for (int k = 0; k < 6; ++k) {
        m[k] += __shfl_xor(m[k], 1, 64);      // merge edge-halves (same relation)
        mo[k] = __shfl_xor(m[k], 2, 64);      // fetch the other relation's sum
    }
    int baseOwn = r * 96, baseOth = (1 - r) * 96;
    float xv[6];
    {
        const float2* xp = reinterpret_cast<const float2*>(x + (size_t)node * 6);
        float2 a = xp[0], b = xp[1], c = xp[2];
        xv[0] = a.x; xv[1] = a.y; xv[2] = b.x; xv[3] = b.y; xv[4] = c.x; xv[5] = c.y;
    }
    int dc = l * 4;
    float acc[4];
    #pragma unroll
    for (int j = 0; j < 4; ++j) acc[j] = sw[288 + dc + j];
    #pragma unroll
    for (int k = 0; k < 6; ++k) {
        #pragma unroll
        for (int j = 0; j < 4; ++j) {
            acc[j] = fmaf(m[k],  sw[baseOwn + k * 16 + dc + j], acc[j]);
            acc[j] = fmaf(mo[k], sw[baseOth + k * 16 + dc + j], acc[j]);
            acc[j] = fmaf(xv[k], sw[192 + k * 16 + dc + j], acc[j]);
        }
    }
    f16x4 o;
    #pragma unroll
    for (int j = 0; j < 4; ++j) o[j] = (f16)acc[j];
    *reinterpret_cast<f16x4*>(h0h + (size_t)node * 16 + dc) = o;
}

// ---------------- fused layer 1: gather -> transform -> h1h + h1q (frozen, round-8) ----------------
__global__ __launch_bounds__(256) void g1t(const int* __restrict__ deg, const int* __restrict__ off,
                                           const int* __restrict__ eidx, const f16* __restrict__ h0h,
                                           const float* __restrict__ wc1, const float* __restrict__ bc1,
                                           f16* __restrict__ h1h, unsigned* __restrict__ h1q)
{
    __shared__ float sw[1536 + 32];
    __shared__ float ms[32][33];              // +1 pad: conflict-free
    for (int t = threadIdx.x; t < 1568; t += 256) sw[t] = (t < 1536) ? wc1[t] : bc1[t - 1536];

    int tid = threadIdx.x;
    int nloc = tid >> 3, l = tid & 7;
    int r = l >> 2, dq = l & 3;
    int node = blockIdx.x * 32 + nloc;

    if (node < NN) {
        int e1 = off[r * NN + node];
        int e0 = e1 - deg[r * NN + node];
        float a0 = 0.f, a1 = 0.f, a2 = 0.f, a3 = 0.f;
        int e = e0;
        for (; e + 4 <= e1; e += 4) {
            int sA = eidx[e], sB = eidx[e + 1], sC = eidx[e + 2], sD = eidx[e + 3];
            f16x4 vA = *reinterpret_cast<const f16x4*>(h0h + (size_t)sA * 16 + dq * 4);
            f16x4 vB = *reinterpret_cast<const f16x4*>(h0h + (size_t)sB * 16 + dq * 4);
            f16x4 vC = *reinterpret_cast<const f16x4*>(h0h + (size_t)sC * 16 + dq * 4);
            f16x4 vD = *reinterpret_cast<const f16x4*>(h0h + (size_t)sD * 16 + dq * 4);
            a0 += (float)vA[0] + (float)vB[0] + (float)vC[0] + (float)vD[0];
            a1 += (float)vA[1] + (float)vB[1] + (float)vC[1] + (float)vD[1];
            a2 += (float)vA[2] + (float)vB[2] + (float)vC[2] + (float)vD[2];
            a3 += (float)vA[3] + (float)vB[3] + (float)vC[3] + (float)vD[3];
        }
        for (; e < e1; ++e) {
            f16x4 v = *reinterpret_cast<const f16x4*>(h0h + (size_t)eidx[e] * 16 + dq * 4);
            a0 += (float)v[0]; a1 += (float)v[1]; a2 += (float)v[2]; a3 += (float)v[3];
        }
        ms[nloc][r * 16 + dq * 4 + 0] = a0;
        ms[nloc][r * 16 + dq * 4 + 1] = a1;
        ms[nloc][r * 16 + dq * 4 + 2] = a2;
        ms[nloc][r * 16 + dq * 4 + 3] = a3;
    }
    __syncthreads();
    if (node >= NN) return;

    // transform: lane l computes output cols l*4 .. l*4+3
    int c0 = l * 4;
    float acc[4];
    #pragma unroll
    for (int j = 0; j < 4; ++j) acc[j] = sw[1536 + c0 + j];
    #pragma unroll
    for (int k = 0; k < 32; ++k) {
        float s = ms[nloc][k];
        #pragma unroll
        for (int j = 0; j < 4; ++j) acc[j] = fmaf(s, sw[k * 32 + c0 + j], acc[j]);
    }
    {
        const f16x8* hp = reinterpret_cast<const f16x8*>(h0h + (size_t)node * 16);
        f16x8 a = hp[0], b = hp[1];
        #pragma unroll
        for (int k = 0; k < 8; ++k) {
            float s0 = (float)a[k], s1 = (float)b[k];
            #pragma unroll
            for (int j = 0; j < 4; ++j)
                acc[j] = fmaf(s0, sw[(32 + k) * 32 + c0 + j], fmaf(s1, sw[(40 + k) * 32 + c0 + j], acc[j]));
        }
    }
    #pragma unroll
    for (int j = 0; j < 4; ++j) acc[j] = fmaxf(acc[j], 0.f);

    f16x4 o;
    #pragma unroll
    for (int j = 0; j < 4; ++j) o[j] = (f16)acc[j];
    *reinterpret_cast<f16x4*>(h1h + (size_t)node * 32 + c0) = o;

    int w0 = __builtin_amdgcn_cvt_pk_fp8_f32(acc[0], acc[1], 0, false);
    w0 = __builtin_amdgcn_cvt_pk_fp8_f32(acc[2], acc[3], w0, true);
    h1q[(size_t)node * 8 + l] = (unsigned)w0;
}

// ---------------- fused layer 2: relation-parallel gather -> LDS tile -> MFMA -> out ----------------
// 4-deep gather (proven 55.3 us, VGPR 48, no spill). Single variable vs round 16:
// launch_bounds (256,4) -> (256,6) to recover the occupancy that dropped 69->44%
// while keeping the deep pipeline (VGPR budget ~85 >> measured 48: cannot spill).
__global__ __launch_bounds__(256, 6) void g2t2(const int* __restrict__ deg, const int* __restrict__ off,
                                               const int* __restrict__ eidx, const unsigned* __restrict__ h1q,
                                               const f16* __restrict__ h1h, const f16* __restrict__ b2frag,
                                               const float* __restrict__ bc2, float* __restrict__ out)
{
    __shared__ f16 cat[16][264];

    int tid = threadIdx.x;
    int nloc = tid >> 4;
    int lane16 = tid & 15;
    int node = blockIdx.x * 16 + nloc;   // 6250 * 16 == NN exactly

    if (lane16 >= 14) {
        int part = lane16 - 14;
        const f16x8* hp = reinterpret_cast<const f16x8*>(h1h + (size_t)node * 32 + part * 16);
        f16x8 v0 = hp[0], v1 = hp[1];
        *reinterpret_cast<f16x8*>(&cat[nloc][224 + part * 16]) = v0;
        *reinterpret_cast<f16x8*>(&cat[nloc][224 + part * 16 + 8]) = v1;
    } else {
        int r = lane16 >> 1;
        int half = lane16 & 1;
        int d = deg[(r + 2) * NN + node];
        int e1 = off[(r + 2) * NN + node];
        int e0 = e1 - d;

        f32x2 acc[8];
        #pragma unroll
        for (int q = 0; q < 8; ++q) acc[q] = (f32x2){0.f, 0.f};

        const uint4* tbl = reinterpret_cast<const uint4*>(h1q);
        int e = e0;
        for (; e + 4 <= e1; e += 4) {          // 4-deep: 4 eidx then 4 table loads in flight
            int sA = eidx[e], sB = eidx[e + 1], sC = eidx[e + 2], sD = eidx[e + 3];
            uint4 qA = tbl[(size_t)sA * 2 + half];
            uint4 qB = tbl[(size_t)sB * 2 + half];
            uint4 qC = tbl[(size_t)sC * 2 + half];
            uint4 qD = tbl[(size_t)sD * 2 + half];
            acc[0] += __builtin_amdgcn_cvt_pk_f32_fp8(qA.x, false);
            acc[1] += __builtin_amdgcn_cvt_pk_f32_fp8(qA.x, true);
            acc[2] += __builtin_amdgcn_cvt_pk_f32_fp8(qA.y, false);
            acc[3] += __builtin_amdgcn_cvt_pk_f32_fp8(qA.y, true);
            acc[4] += __builtin_amdgcn_cvt_pk_f32_fp8(qA.z, false);
            acc[5] += __builtin_amdgcn_cvt_pk_f32_fp8(qA.z, true);
            acc[6] += __builtin_amdgcn_cvt_pk_f32_fp8(qA.w, false);
            acc[7] += __builtin_amdgcn_cvt_pk_f32_fp8(qA.w, true);
            acc[0] += __builtin_amdgcn_cvt_pk_f32_fp8(qB.x, false);
            acc[1] += __builtin_amdgcn_cvt_pk_f32_fp8(qB.x, true);
            acc[2] += __builtin_amdgcn_cvt_pk_f32_fp8(qB.y, false);
            acc[3] += __builtin_amdgcn_cvt_pk_f32_fp8(qB.y, true);
            acc[4] += __builtin_amdgcn_cvt_pk_f32_fp8(qB.z, false);
            acc[5] += __builtin_amdgcn_cvt_pk_f32_fp8(qB.z, true);
            acc[6] += __builtin_amdgcn_cvt_pk_f32_fp8(qB.w, false);
            acc[7] += __builtin_amdgcn_cvt_pk_f32_fp8(qB.w, true);
            acc[0] += __builtin_amdgcn_cvt_pk_f32_fp8(qC.x, false);
            acc[1] += __builtin_amdgcn_cvt_pk_f32_fp8(qC.x, true);
            acc[2] += __builtin_amdgcn_cvt_pk_f32_fp8(qC.y, false);
            acc[3] += __builtin_amdgcn_cvt_pk_f32_fp8(qC.y, true);
            acc[4] += __builtin_amdgcn_cvt_pk_f32_fp8(qC.z, false);
            acc[5] += __builtin_amdgcn_cvt_pk_f32_fp8(qC.z, true);
            acc[6] += __builtin_amdgcn_cvt_pk_f32_fp8(qC.w, false);
            acc[7] += __builtin_amdgcn_cvt_pk_f32_fp8(qC.w, true);
            acc[0] += __builtin_amdgcn_cvt_pk_f32_fp8(qD.x, false);
            acc[1] += __builtin_amdgcn_cvt_pk_f32_fp8(qD.x, true);
            acc[2] += __builtin_amdgcn_cvt_pk_f32_fp8(qD.y, false);
            acc[3] += __builtin_amdgcn_cvt_pk_f32_fp8(qD.y, true);
            acc[4] += __builtin_amdgcn_cvt_pk_f32_fp8(qD.z, false);
            acc[5] += __builtin_amdgcn_cvt_pk_f32_fp8(qD.z, true);
            acc[6] += __builtin_amdgcn_cvt_pk_f32_fp8(qD.w, false);
            acc[7] += __builtin_amdgcn_cvt_pk_f32_fp8(qD.w, true);
        }
        for (; e + 2 <= e1; e += 2) {
            int sA = eidx[e], sB = eidx[e + 1];
            uint4 qA = tbl[(size_t)sA * 2 + half];
            uint4 qB = tbl[(size_t)sB * 2 + half];
            acc[0] += __builtin_amdgcn_cvt_pk_f32_fp8(qA.x, false);
            acc[1] += __builtin_amdgcn_cvt_pk_f32_fp8(qA.x, true);
            acc[2] += __builtin_amdgcn_cvt_pk_f32_fp8(qA.y, false);
            acc[3] += __builtin_amdgcn_cvt_pk_f32_fp8(qA.y, true);
            acc[4] += __builtin_amdgcn_cvt_pk_f32_fp8(qA.z, false);
            acc[5] += __builtin_amdgcn_cvt_pk_f32_fp8(qA.z, true);
            acc[6] += __builtin_amdgcn_cvt_pk_f32_fp8(qA.w, false);
            acc[7] += __builtin_amdgcn_cvt_pk_f32_fp8(qA.w, true);
            acc[0] += __builtin_amdgcn_cvt_pk_f32_fp8(qB.x, false);
            acc[1] += __builtin_amdgcn_cvt_pk_f32_fp8(qB.x, true);
            acc[2] += __builtin_amdgcn_cvt_pk_f32_fp8(qB.y, false);
            acc[3] += __builtin_amdgcn_cvt_pk_f32_fp8(qB.y, true);
            acc[4] += __builtin_amdgcn_cvt_pk_f32_fp8(qB.z, false);
            acc[5] += __builtin_amdgcn_cvt_pk_f32_fp8(qB.z, true);
            acc[6] += __builtin_amdgcn_cvt_pk_f32_fp8(qB.w, false);
            acc[7] += __builtin_amdgcn_cvt_pk_f32_fp8(qB.w, true);
        }
        if (e < e1) {
            int sA = eidx[e];
            uint4 qA = tbl[(size_t)sA * 2 + half];
            acc[0] += __builtin_amdgcn_cvt_pk_f32_fp8(qA.x, false);
            acc[1] += __builtin_amdgcn_cvt_pk_f32_fp8(qA.x, true);
            acc[2] += __builtin_amdgcn_cvt_pk_f32_fp8(qA.y, false);
            acc[3] += __builtin_amdgcn_cvt_pk_f32_fp8(qA.y, true);
            acc[4] += __builtin_amdgcn_cvt_pk_f32_fp8(qA.z, false);
            acc[5] += __builtin_amdgcn_cvt_pk_f32_fp8(qA.z, true);
            acc[6] += __builtin_amdgcn_cvt_pk_f32_fp8(qA.w, false);
            acc[7] += __builtin_amdgcn_cvt_pk_f32_fp8(qA.w, true);
        }

        float sc = (r == 2 || r == 3 || r == 6) ? (1.0f / (float)max(d, 1)) : 1.0f;
        f16x8 o0, o1;
        #pragma unroll
        for (int q = 0; q < 4; ++q) {
            o0[q * 2 + 0] = (f16)(acc[q][0] * sc);
            o0[q * 2 + 1] = (f16)(acc[q][1] * sc);
            o1[q * 2 + 0] = (f16)(acc[4 + q][0] * sc);
            o1[q * 2 + 1] = (f16)(acc[4 + q][1] * sc);
        }
        *reinterpret_cast<f16x8*>(&cat[nloc][r * 32 + half * 16]) = o0;
        *reinterpret_cast<f16x8*>(&cat[nloc][r * 32 + half * 16 + 8]) = o1;
    }

    int lane = tid & 63, w = tid >> 6;
    int quad = lane >> 4, col0 = lane & 15;
    float bcv = bc2[w * 16 + col0];

    f16x8 bfr[8];
    #pragma unroll
    for (int kt = 0; kt < 8; ++kt)
        bfr[kt] = *reinterpret_cast<const f16x8*>(b2frag + ((size_t)(kt * 4 + w) * 64 + lane) * 8);

    __syncthreads();

    f32x4 acc = (f32x4){0.f, 0.f, 0.f, 0.f};
    #pragma unroll
    for (int kt = 0; kt < 8; ++kt) {
        f16x8 a = *reinterpret_cast<const f16x8*>(&cat[col0][kt * 32 + quad * 8]);
        acc = __builtin_amdgcn_mfma_f32_16x16x32_f16(a, bfr[kt], acc, 0, 0, 0);
    }

    int row0 = blockIdx.x * 16 + quad * 4;
    #pragma unroll
    for (int i = 0; i < 4; ++i)
        out[(size_t)(row0 + i) * 64 + w * 16 + col0] = fmaxf(acc[i] + bcv, 0.f);
}

// ---------------- launch ----------------
extern "C" void kernel_launch(void* const* d_in, const int* in_sizes, int n_in,
                              void* d_out, int out_size, void* d_ws, size_t ws_size,
                              hipStream_t stream)
{
    const float* x = (const float*)d_in[0];
    EPtrs ep;
    for (int i = 0; i < 9; ++i) { const int* p = (const int*)d_in[1 + i]; ep.s[i] = p; ep.d[i] = p + NE; }
    const float* W0n = (const float*)d_in[10]; const float* W0r = (const float*)d_in[11];
    const float* b0  = (const float*)d_in[12];
    const float* W1n = (const float*)d_in[13]; const float* W1r = (const float*)d_in[14];
    const float* b1  = (const float*)d_in[15];
    const float* P1  = (const float*)d_in[16]; const float* pb1 = (const float*)d_in[17];
    const float* W2n = (const float*)d_in[18]; const float* W2r = (const float*)d_in[19];
    const float* b2  = (const float*)d_in[20];
    const float* P2  = (const float*)d_in[21]; const float* pb2 = (const float*)d_in[22];
    float* out = (float*)d_out;
    char* ws = (char*)d_ws;

    size_t off_b = 0;
    auto alloc = [&](size_t b) { size_t o = off_b; off_b += (b + 255) & ~(size_t)255; return o; };
    size_t o_wc0 = alloc(288 * 4);   size_t o_bc0 = alloc(16 * 4);
    size_t o_wc1 = alloc(1536 * 4);  size_t o_bc1 = alloc(32 * 4);
    size_t o_b2f = alloc(16384 * 2); size_t o_bc2 = alloc(64 * 4);
    size_t o_h0h = alloc((size_t)NN * 16 * 2);
    size_t o_h1q = alloc((size_t)NN * 32);             // fp8 e4m3 gather table (3.2 MB)
    size_t o_h1h = alloc((size_t)NN * 32 * 2);         // compact h1 f16 (6.4 MB)
    size_t o_bin = alloc((size_t)NBIN * CAP * 4);      // 37.7 MB
    size_t o_deg = alloc((size_t)9 * NN * 4);
    size_t o_off = alloc((size_t)9 * NN * 4);
    size_t o_eid = alloc((size_t)NBIN * CAP * 4);      // 37.7 MB
    size_t o_cur = alloc((size_t)NBIN * 4);
    (void)ws_size;  // ~96 MB total

    float* wc0 = (float*)(ws + o_wc0); float* bc0 = (float*)(ws + o_bc0);
    float* wc1 = (float*)(ws + o_wc1); float* bc1 = (float*)(ws + o_bc1);
    f16*   b2f = (f16*)(ws + o_b2f);   float* bc2 = (float*)(ws + o_bc2);
    f16*   h0h = (f16*)(ws + o_h0h);
    unsigned* h1q = (unsigned*)(ws + o_h1q);
    f16*   h1h = (f16*)(ws + o_h1h);
    unsigned* binbuf = (unsigned*)(ws + o_bin);
    int*   deg = (int*)(ws + o_deg);
    int*   offp = (int*)(ws + o_off);
    int*   eid = (int*)(ws + o_eid);
    int*   cur = (int*)(ws + o_cur);

    dim3 B(256);
    prep_weights<<<32, B, 0, stream>>>(W0n, W0r, b0, W1n, W1r, b1, P1, pb1,
                                       W2n, W2r, b2, P2, pb2,
                                       wc0, bc0, wc1, bc1, b2f, bc2, cur);
    passA<<<dim3((NE + ACH - 1) / ACH, 9), dim3(ABD), 0, stream>>>(ep, cur, binbuf);
    passB<<<NBIN, B, 0, stream>>>(binbuf, cur, deg, offp, eid);

    t0f<<<(NN * 4 + 255) / 256, B, 0, stream>>>(x, deg, offp, eid, wc0, bc0, h0h);
    g1t<<<(NN + 31) / 32, B, 0, stream>>>(deg, offp, eid, h0h, wc1, bc1, h1h, h1q);
    g2t2<<<NN / 16, B, 0, stream>>>(deg, offp, eid, h1q, h1h, b2f, bc2, out);
}

// Round 18
// 271.029 us; speedup vs baseline: 1.1207x; 1.1207x over previous
//
#include <hip/hip_runtime.h>

#define NN 100000
#define NE 800000
#define NRG 256       // dst ranges per relation
#define SPAN 392      // nodes per range (256*392 = 100352 >= NN)
#define CAP 4096      // capacity per (relation,range) bin; mean 3125, +17 sigma
#define NBIN (9 * NRG)
#define ACH 8192      // passA edges per block (runs avg 32 -> 128B write segments)
#define ABD 512       // passA block size (8 waves; 43KB LDS -> 3 blocks/CU)

typedef _Float16 f16;
typedef __attribute__((ext_vector_type(4))) _Float16 f16x4;
typedef __attribute__((ext_vector_type(8))) _Float16 f16x8;
typedef __attribute__((ext_vector_type(4))) float f32x4;
typedef __attribute__((ext_vector_type(2))) float f32x2;

#define NTL(p) __builtin_nontemporal_load(p)

struct EPtrs { const int* s[9]; const int* d[9]; };

// ---------------- prep: combined weights + cursor zero ----------------
__global__ __launch_bounds__(256) void prep_weights(
    const float* __restrict__ W0n, const float* __restrict__ W0r, const float* __restrict__ b0,
    const float* __restrict__ W1n, const float* __restrict__ W1r, const float* __restrict__ b1,
    const float* __restrict__ P1,  const float* __restrict__ pb1,
    const float* __restrict__ W2n, const float* __restrict__ W2r, const float* __restrict__ b2,
    const float* __restrict__ P2,  const float* __restrict__ pb2,
    float* __restrict__ wc0, float* __restrict__ bc0,
    float* __restrict__ wc1, float* __restrict__ bc1,
    f16*   __restrict__ b2frag, float* __restrict__ bc2,
    int*   __restrict__ cursor)
{
    int gtid = blockIdx.x * 256 + threadIdx.x;
    int gstr = gridDim.x * 256;

    for (int t = gtid; t < NBIN; t += gstr) cursor[t] = 0;

    for (int t = gtid; t < 18 * 16; t += gstr) {
        int row = t >> 4, col = t & 15;
        float v;
        if (row < 6)       v = W0n[row * 16 + col];
        else if (row < 12) v = W0n[96 + (row - 6) * 16 + col];
        else               v = W0r[(row - 12) * 16 + col] + W0r[96 + (row - 12) * 16 + col];
        wc0[t] = v;
    }
    for (int t = gtid; t < 16; t += gstr) bc0[t] = b0[t] + b0[16 + t];

    for (int t = gtid; t < 48 * 32; t += gstr) {
        int row = t >> 5, col = t & 31;
        float v;
        if (row < 16)      v = W1n[row * 32 + col];
        else if (row < 32) v = W1n[512 + (row - 16) * 32 + col];
        else { int rr = row - 32; v = W1r[rr * 32 + col] + W1r[512 + rr * 32 + col] + P1[rr * 32 + col]; }
        wc1[t] = v;
    }
    for (int t = gtid; t < 32; t += gstr) bc1[t] = b1[t] + b1[32 + t] + pb1[t];

    for (int t = gtid; t < 256 * 64; t += gstr) {
        int j = t & 7, lane = (t >> 3) & 63, ntk = t >> 9;
        int nt = ntk & 3, kt = ntk >> 2;
        int k = kt * 32 + (lane >> 4) * 8 + j;
        int n = nt * 16 + (lane & 15);
        float v;
        if (k < 224) v = W2n[k * 64 + n];
        else {
            int rr = k - 224;
            v = P2[rr * 64 + n];
            #pragma unroll
            for (int r = 0; r < 7; ++r) v += W2r[r * 2048 + rr * 64 + n];
        }
        b2frag[t] = (f16)v;
    }
    for (int t = gtid; t < 64; t += gstr) {
        float v = pb2[t];
        #pragma unroll
        for (int r = 0; r < 7; ++r) v += b2[r * 64 + t];
        bc2[t] = v;
    }
}

// ---------------- pass A: bucket edges by dst range (frozen, round-13) ----------------
__global__ __launch_bounds__(ABD) void passA(EPtrs ep, int* __restrict__ cursor,
                                             unsigned* __restrict__ binbuf)
{
    int r = blockIdx.y;
    int e0 = blockIdx.x * ACH;
    int cnt = min(ACH, NE - e0);
    int tid = threadIdx.x;
    __shared__ int h[NRG];
    __shared__ int bs[NRG];
    __shared__ int gb[NRG];
    __shared__ int wsumA[4];
    __shared__ unsigned pk[ACH];
    __shared__ unsigned char pkb[ACH];

    if (tid < NRG) h[tid] = 0;
    __syncthreads();

    const int* dp = ep.d[r];
    const int* sp = ep.s[r];
    unsigned wv[16];            // ACH/ABD == 16
    int rgk[16];
    int lrk[16];
    #pragma unroll
    for (int k = 0; k < 16; ++k) {
        int e = e0 + k * ABD + tid;
        rgk[k] = -1;
        if (e < NE) {
            int d = NTL(dp + e);
            int sv = NTL(sp + e);
            int g = d / SPAN;
            int l = d - g * SPAN;
            wv[k] = ((unsigned)l << 17) | (unsigned)sv;
            rgk[k] = g;
            lrk[k] = atomicAdd(&h[g], 1);
        }
    }
    __syncthreads();

    // scan of 256 counts in waves 0-3
    int vcnt = 0, incl = 0;
    int lane = tid & 63, wid = tid >> 6;
    if (tid < NRG) {
        vcnt = h[tid];
        incl = vcnt;
        #pragma unroll
        for (int ofs = 1; ofs < 64; ofs <<= 1) {
            int u = __shfl_up(incl, ofs, 64);
            if (lane >= ofs) incl += u;
        }
        if (lane == 63) wsumA[wid] = incl;
    }
    __syncthreads();
    if (tid == 0) {
        int a = wsumA[0], b = wsumA[1], c = wsumA[2];
        wsumA[0] = 0; wsumA[1] = a; wsumA[2] = a + b; wsumA[3] = a + b + c;
    }
    __syncthreads();
    if (tid < NRG) {
        int excl = incl - vcnt + wsumA[wid];
        bs[tid] = excl;
        gb[tid] = (vcnt > 0) ? atomicAdd(&cursor[r * NRG + tid], vcnt) : 0;
    }
    __syncthreads();

    #pragma unroll
    for (int k = 0; k < 16; ++k) {
        if (rgk[k] >= 0) {
            int p = bs[rgk[k]] + lrk[k];
            pk[p] = wv[k];
            pkb[p] = (unsigned char)rgk[k];
        }
    }
    __syncthreads();

    for (int i = tid; i < cnt; i += ABD) {
        int g = pkb[i];
        int pos = gb[g] + (i - bs[g]);
        if (pos < CAP)
            binbuf[((size_t)(r * NRG + g)) * CAP + pos] = pk[i];
    }
}

// ---------------- pass B: per-bin counting sort (hybrid, frozen) ----------------
__global__ __launch_bounds__(256) void passB(const unsigned* __restrict__ binbuf,
                                             const int* __restrict__ cursor,
                                             int* __restrict__ deg, int* __restrict__ off,
                                             int* __restrict__ eidx)
{
    int bin = blockIdx.x;
    int r = bin >> 8, rg = bin & (NRG - 1);
    int lo = rg * SPAN;
    int n_here = min(SPAN, NN - lo);
    int tid = threadIdx.x;
    __shared__ int h[SPAN];
    __shared__ int wsum[4];
    __shared__ int stage[CAP];

    int sz = min(cursor[bin], CAP);
    const unsigned* bp = binbuf + (size_t)bin * CAP;

    for (int i = tid; i < SPAN; i += 256) h[i] = 0;
    __syncthreads();

    unsigned wv[16];      // CAP/256 == 16: statically indexed (stays in VGPRs)
    int rk[16];
    #pragma unroll
    for (int k = 0; k < 16; ++k) {
        int e = tid + k * 256;
        if (e < sz) {
            unsigned w = NTL(bp + e);
            wv[k] = w;
            rk[k] = atomicAdd(&h[w >> 17], 1);
        }
    }
    __syncthreads();

    // scan counts -> row starts (in h); write deg / row-end off (2 per thread)
    int i0 = tid * 2;
    int dstash[2];
    int s = 0;
    #pragma unroll
    for (int k = 0; k < 2; ++k) {
        int i = i0 + k;
        int v = (i < SPAN) ? h[i] : 0;
        dstash[k] = v;
        s += v;
    }
    int lane = tid & 63, wid = tid >> 6;
    int incl = s;
    #pragma unroll
    for (int ofs = 1; ofs < 64; ofs <<= 1) {
        int u = __shfl_up(incl, ofs, 64);
        if (lane >= ofs) incl += u;
    }
    if (lane == 63) wsum[wid] = incl;
    __syncthreads();
    if (tid == 0) {
        int a = wsum[0], b = wsum[1], c = wsum[2];
        wsum[0] = 0; wsum[1] = a; wsum[2] = a + b; wsum[3] = a + b + c;
    }
    __syncthreads();
    int run = incl - s + wsum[wid];
    int base = bin * CAP;
    #pragma unroll
    for (int k = 0; k < 2; ++k) {
        int i = i0 + k;
        if (i < SPAN) {
            int v = dstash[k];
            h[i] = run;
            if (i < n_here) {
                deg[r * NN + lo + i] = v;
                off[r * NN + lo + i] = base + run + v;   // absolute row end
            }
            run += v;
        }
    }
    __syncthreads();

    // LDS scatter by rank, then coalesced copy out
    #pragma unroll
    for (int k = 0; k < 16; ++k) {
        int e = tid + k * 256;
        if (e < sz) {
            unsigned w = wv[k];
            stage[h[w >> 17] + rk[k]] = (int)(w & 0x1FFFF);
        }
    }
    __syncthreads();
    for (int i = tid; i < sz; i += 256) eidx[base + i] = stage[i];
}

// ---------------- layer 0: x(6) -> h0h(16 f16); 4 lanes/node (frozen) ----------------
__global__ __launch_bounds__(256) void t0f(const float* __restrict__ x,
                                           const int* __restrict__ deg, const int* __restrict__ off,
                                           const int* __restrict__ eidx,
                                           const float* __restrict__ wc0, const float* __restrict__ bc0,
                                           f16* __restrict__ h0h)
{
    __shared__ float sw[288 + 16];
    for (int t = threadIdx.x; t < 304; t += 256) sw[t] = (t < 288) ? wc0[t] : bc0[t - 288];
    __syncthreads();
    int t = blockIdx.x * 256 + threadIdx.x;
    int node = t >> 2;
    if (node >= NN) return;
    int l = t & 3;
    int r = l >> 1, p = l & 1;

    float m[6] = {0, 0, 0, 0, 0, 0};
    {
        int e1 = off[r * NN + node];
        int e0 = e1 - deg[r * NN + node];
        int e = e0 + p;                       // strided half: lanes p=0/1 interleave
        for (; e + 2 < e1; e += 4) {
            int sA = eidx[e], sB = eidx[e + 2];
            const float2* pA = reinterpret_cast<const float2*>(x + (size_t)sA * 6);
            const float2* pB = reinterpret_cast<const float2*>(x + (size_t)sB * 6);
            float2 a0 = pA[0], a1 = pA[1], a2 = pA[2];
            float2 b0 = pB[0], b1 = pB[1], b2 = pB[2];
            m[0] += a0.x + b0.x; m[1] += a0.y + b0.y;
            m[2] += a1.x + b1.x; m[3] += a1.y + b1.y;
            m[4] += a2.x + b2.x; m[5] += a2.y + b2.y;
        }
        if (e < e1) {
            int sA = eidx[e];
            const float2* pA = reinterpret_cast<const float2*>(x + (size_t)sA * 6);
            float2 a0 = pA[0], a1 = pA[1], a2 = pA[2];
            m[0] += a0.x; m[1] += a0.y; m[2] += a1.x; m[3] += a1.y; m[4] += a2.x; m[5] += a2.y;
        }
    }
    float mo[6];
    #pragma unroll
    for (int k = 0; k < 6; ++k) {
        m[k] += __shfl_xor(m[k], 1, 64);      // merge edge-halves (same relation)
        mo[k] = __shfl_xor(m[k], 2, 64);      // fetch the other relation's sum
    }
    int baseOwn = r * 96, baseOth = (1 - r) * 96;
    float xv[6];
    {
        const float2* xp = reinterpret_cast<const float2*>(x + (size_t)node * 6);
        float2 a = xp[0], b = xp[1], c = xp[2];
        xv[0] = a.x; xv[1] = a.y; xv[2] = b.x; xv[3] = b.y; xv[4] = c.x; xv[5] = c.y;
    }
    int dc = l * 4;
    float acc[4];
    #pragma unroll
    for (int j = 0; j < 4; ++j) acc[j] = sw[288 + dc + j];
    #pragma unroll
    for (int k = 0; k < 6; ++k) {
        #pragma unroll
        for (int j = 0; j < 4; ++j) {
            acc[j] = fmaf(m[k],  sw[baseOwn + k * 16 + dc + j], acc[j]);
            acc[j] = fmaf(mo[k], sw[baseOth + k * 16 + dc + j], acc[j]);
            acc[j] = fmaf(xv[k], sw[192 + k * 16 + dc + j], acc[j]);
        }
    }
    f16x4 o;
    #pragma unroll
    for (int j = 0; j < 4; ++j) o[j] = (f16)acc[j];
    *reinterpret_cast<f16x4*>(h0h + (size_t)node * 16 + dc) = o;
}

// ---------------- fused layer 1: gather -> transform -> h1h + h1q (frozen, round-8) ----------------
__global__ __launch_bounds__(256) void g1t(const int* __restrict__ deg, const int* __restrict__ off,
                                           const int* __restrict__ eidx, const f16* __restrict__ h0h,
                                           const float* __restrict__ wc1, const float* __restrict__ bc1,
                                           f16* __restrict__ h1h, unsigned* __restrict__ h1q)
{
    __shared__ float sw[1536 + 32];
    __shared__ float ms[32][33];              // +1 pad: conflict-free
    for (int t = threadIdx.x; t < 1568; t += 256) sw[t] = (t < 1536) ? wc1[t] : bc1[t - 1536];

    int tid = threadIdx.x;
    int nloc = tid >> 3, l = tid & 7;
    int r = l >> 2, dq = l & 3;
    int node = blockIdx.x * 32 + nloc;

    if (node < NN) {
        int e1 = off[r * NN + node];
        int e0 = e1 - deg[r * NN + node];
        float a0 = 0.f, a1 = 0.f, a2 = 0.f, a3 = 0.f;
        int e = e0;
        for (; e + 4 <= e1; e += 4) {
            int sA = eidx[e], sB = eidx[e + 1], sC = eidx[e + 2], sD = eidx[e + 3];
            f16x4 vA = *reinterpret_cast<const f16x4*>(h0h + (size_t)sA * 16 + dq * 4);
            f16x4 vB = *reinterpret_cast<const f16x4*>(h0h + (size_t)sB * 16 + dq * 4);
            f16x4 vC = *reinterpret_cast<const f16x4*>(h0h + (size_t)sC * 16 + dq * 4);
            f16x4 vD = *reinterpret_cast<const f16x4*>(h0h + (size_t)sD * 16 + dq * 4);
            a0 += (float)vA[0] + (float)vB[0] + (float)vC[0] + (float)vD[0];
            a1 += (float)vA[1] + (float)vB[1] + (float)vC[1] + (float)vD[1];
            a2 += (float)vA[2] + (float)vB[2] + (float)vC[2] + (float)vD[2];
            a3 += (float)vA[3] + (float)vB[3] + (float)vC[3] + (float)vD[3];
        }
        for (; e < e1; ++e) {
            f16x4 v = *reinterpret_cast<const f16x4*>(h0h + (size_t)eidx[e] * 16 + dq * 4);
            a0 += (float)v[0]; a1 += (float)v[1]; a2 += (float)v[2]; a3 += (float)v[3];
        }
        ms[nloc][r * 16 + dq * 4 + 0] = a0;
        ms[nloc][r * 16 + dq * 4 + 1] = a1;
        ms[nloc][r * 16 + dq * 4 + 2] = a2;
        ms[nloc][r * 16 + dq * 4 + 3] = a3;
    }
    __syncthreads();
    if (node >= NN) return;

    // transform: lane l computes output cols l*4 .. l*4+3
    int c0 = l * 4;
    float acc[4];
    #pragma unroll
    for (int j = 0; j < 4; ++j) acc[j] = sw[1536 + c0 + j];
    #pragma unroll
    for (int k = 0; k < 32; ++k) {
        float s = ms[nloc][k];
        #pragma unroll
        for (int j = 0; j < 4; ++j) acc[j] = fmaf(s, sw[k * 32 + c0 + j], acc[j]);
    }
    {
        const f16x8* hp = reinterpret_cast<const f16x8*>(h0h + (size_t)node * 16);
        f16x8 a = hp[0], b = hp[1];
        #pragma unroll
        for (int k = 0; k < 8; ++k) {
            float s0 = (float)a[k], s1 = (float)b[k];
            #pragma unroll
            for (int j = 0; j < 4; ++j)
                acc[j] = fmaf(s0, sw[(32 + k) * 32 + c0 + j], fmaf(s1, sw[(40 + k) * 32 + c0 + j], acc[j]));
        }
    }
    #pragma unroll
    for (int j = 0; j < 4; ++j) acc[j] = fmaxf(acc[j], 0.f);

    f16x4 o;
    #pragma unroll
    for (int j = 0; j < 4; ++j) o[j] = (f16)acc[j];
    *reinterpret_cast<f16x4*>(h1h + (size_t)node * 32 + c0) = o;

    int w0 = __builtin_amdgcn_cvt_pk_fp8_f32(acc[0], acc[1], 0, false);
    w0 = __builtin_amdgcn_cvt_pk_fp8_f32(acc[2], acc[3], w0, true);
    h1q[(size_t)node * 8 + l] = (unsigned)w0;
}

// ---------------- fused layer 2: relation-parallel gather -> LDS tile -> MFMA -> out ----------------
// FINAL proven form (round 16, 272.7 us total): 4-deep gather + launch_bounds(256,4).
// The only no-spill cell: (256,8) caps at 64 and spills (round 14: FETCH 424 MB);
// (256,6) squeezes allocator to 40 and spills (round 17: FETCH 163 MB). At (256,4)
// the allocator lands at 48 VGPR organically -- clean counters, 55.3 us.
__global__ __launch_bounds__(256, 4) void g2t2(const int* __restrict__ deg, const int* __restrict__ off,
                                               const int* __restrict__ eidx, const unsigned* __restrict__ h1q,
                                               const f16* __restrict__ h1h, const f16* __restrict__ b2frag,
                                               const float* __restrict__ bc2, float* __restrict__ out)
{
    __shared__ f16 cat[16][264];

    int tid = threadIdx.x;
    int nloc = tid >> 4;
    int lane16 = tid & 15;
    int node = blockIdx.x * 16 + nloc;   // 6250 * 16 == NN exactly

    if (lane16 >= 14) {
        int part = lane16 - 14;
        const f16x8* hp = reinterpret_cast<const f16x8*>(h1h + (size_t)node * 32 + part * 16);
        f16x8 v0 = hp[0], v1 = hp[1];
        *reinterpret_cast<f16x8*>(&cat[nloc][224 + part * 16]) = v0;
        *reinterpret_cast<f16x8*>(&cat[nloc][224 + part * 16 + 8]) = v1;
    } else {
        int r = lane16 >> 1;
        int half = lane16 & 1;
        int d = deg[(r + 2) * NN + node];
        int e1 = off[(r + 2) * NN + node];
        int e0 = e1 - d;

        f32x2 acc[8];
        #pragma unroll
        for (int q = 0; q < 8; ++q) acc[q] = (f32x2){0.f, 0.f};

        const uint4* tbl = reinterpret_cast<const uint4*>(h1q);
        int e = e0;
        for (; e + 4 <= e1; e += 4) {          // 4-deep: 4 eidx then 4 table loads in flight
            int sA = eidx[e], sB = eidx[e + 1], sC = eidx[e + 2], sD = eidx[e + 3];
            uint4 qA = tbl[(size_t)sA * 2 + half];
            uint4 qB = tbl[(size_t)sB * 2 + half];
            uint4 qC = tbl[(size_t)sC * 2 + half];
            uint4 qD = tbl[(size_t)sD * 2 + half];
            acc[0] += __builtin_amdgcn_cvt_pk_f32_fp8(qA.x, false);
            acc[1] += __builtin_amdgcn_cvt_pk_f32_fp8(qA.x, true);
            acc[2] += __builtin_amdgcn_cvt_pk_f32_fp8(qA.y, false);
            acc[3] += __builtin_amdgcn_cvt_pk_f32_fp8(qA.y, true);
            acc[4] += __builtin_amdgcn_cvt_pk_f32_fp8(qA.z, false);
            acc[5] += __builtin_amdgcn_cvt_pk_f32_fp8(qA.z, true);
            acc[6] += __builtin_amdgcn_cvt_pk_f32_fp8(qA.w, false);
            acc[7] += __builtin_amdgcn_cvt_pk_f32_fp8(qA.w, true);
            acc[0] += __builtin_amdgcn_cvt_pk_f32_fp8(qB.x, false);
            acc[1] += __builtin_amdgcn_cvt_pk_f32_fp8(qB.x, true);
            acc[2] += __builtin_amdgcn_cvt_pk_f32_fp8(qB.y, false);
            acc[3] += __builtin_amdgcn_cvt_pk_f32_fp8(qB.y, true);
            acc[4] += __builtin_amdgcn_cvt_pk_f32_fp8(qB.z, false);
            acc[5] += __builtin_amdgcn_cvt_pk_f32_fp8(qB.z, true);
            acc[6] += __builtin_amdgcn_cvt_pk_f32_fp8(qB.w, false);
            acc[7] += __builtin_amdgcn_cvt_pk_f32_fp8(qB.w, true);
            acc[0] += __builtin_amdgcn_cvt_pk_f32_fp8(qC.x, false);
            acc[1] += __builtin_amdgcn_cvt_pk_f32_fp8(qC.x, true);
            acc[2] += __builtin_amdgcn_cvt_pk_f32_fp8(qC.y, false);
            acc[3] += __builtin_amdgcn_cvt_pk_f32_fp8(qC.y, true);
            acc[4] += __builtin_amdgcn_cvt_pk_f32_fp8(qC.z, false);
            acc[5] += __builtin_amdgcn_cvt_pk_f32_fp8(qC.z, true);
            acc[6] += __builtin_amdgcn_cvt_pk_f32_fp8(qC.w, false);
            acc[7] += __builtin_amdgcn_cvt_pk_f32_fp8(qC.w, true);
            acc[0] += __builtin_amdgcn_cvt_pk_f32_fp8(qD.x, false);
            acc[1] += __builtin_amdgcn_cvt_pk_f32_fp8(qD.x, true);
            acc[2] += __builtin_amdgcn_cvt_pk_f32_fp8(qD.y, false);
            acc[3] += __builtin_amdgcn_cvt_pk_f32_fp8(qD.y, true);
            acc[4] += __builtin_amdgcn_cvt_pk_f32_fp8(qD.z, false);
            acc[5] += __builtin_amdgcn_cvt_pk_f32_fp8(qD.z, true);
            acc[6] += __builtin_amdgcn_cvt_pk_f32_fp8(qD.w, false);
            acc[7] += __builtin_amdgcn_cvt_pk_f32_fp8(qD.w, true);
        }
        for (; e + 2 <= e1; e += 2) {
            int sA = eidx[e], sB = eidx[e + 1];
            uint4 qA = tbl[(size_t)sA * 2 + half];
            uint4 qB = tbl[(size_t)sB * 2 + half];
            acc[0] += __builtin_amdgcn_cvt_pk_f32_fp8(qA.x, false);
            acc[1] += __builtin_amdgcn_cvt_pk_f32_fp8(qA.x, true);
            acc[2] += __builtin_amdgcn_cvt_pk_f32_fp8(qA.y, false);
            acc[3] += __builtin_amdgcn_cvt_pk_f32_fp8(qA.y, true);
            acc[4] += __builtin_amdgcn_cvt_pk_f32_fp8(qA.z, false);
            acc[5] += __builtin_amdgcn_cvt_pk_f32_fp8(qA.z, true);
            acc[6] += __builtin_amdgcn_cvt_pk_f32_fp8(qA.w, false);
            acc[7] += __builtin_amdgcn_cvt_pk_f32_fp8(qA.w, true);
            acc[0] += __builtin_amdgcn_cvt_pk_f32_fp8(qB.x, false);
            acc[1] += __builtin_amdgcn_cvt_pk_f32_fp8(qB.x, true);
            acc[2] += __builtin_amdgcn_cvt_pk_f32_fp8(qB.y, false);
            acc[3] += __builtin_amdgcn_cvt_pk_f32_fp8(qB.y, true);
            acc[4] += __builtin_amdgcn_cvt_pk_f32_fp8(qB.z, false);
            acc[5] += __builtin_amdgcn_cvt_pk_f32_fp8(qB.z, true);
            acc[6] += __builtin_amdgcn_cvt_pk_f32_fp8(qB.w, false);
            acc[7] += __builtin_amdgcn_cvt_pk_f32_fp8(qB.w, true);
        }
        if (e < e1) {
            int sA = eidx[e];
            uint4 qA = tbl[(size_t)sA * 2 + half];
            acc[0] += __builtin_amdgcn_cvt_pk_f32_fp8(qA.x, false);
            acc[1] += __builtin_amdgcn_cvt_pk_f32_fp8(qA.x, true);
            acc[2] += __builtin_amdgcn_cvt_pk_f32_fp8(qA.y, false);
            acc[3] += __builtin_amdgcn_cvt_pk_f32_fp8(qA.y, true);
            acc[4] += __builtin_amdgcn_cvt_pk_f32_fp8(qA.z, false);
            acc[5] += __builtin_amdgcn_cvt_pk_f32_fp8(qA.z, true);
            acc[6] += __builtin_amdgcn_cvt_pk_f32_fp8(qA.w, false);
            acc[7] += __builtin_amdgcn_cvt_pk_f32_fp8(qA.w, true);
        }

        float sc = (r == 2 || r == 3 || r == 6) ? (1.0f / (float)max(d, 1)) : 1.0f;
        f16x8 o0, o1;
        #pragma unroll
        for (int q = 0; q < 4; ++q) {
            o0[q * 2 + 0] = (f16)(acc[q][0] * sc);
            o0[q * 2 + 1] = (f16)(acc[q][1] * sc);
            o1[q * 2 + 0] = (f16)(acc[4 + q][0] * sc);
            o1[q * 2 + 1] = (f16)(acc[4 + q][1] * sc);
        }
        *reinterpret_cast<f16x8*>(&cat[nloc][r * 32 + half * 16]) = o0;
        *reinterpret_cast<f16x8*>(&cat[nloc][r * 32 + half * 16 + 8]) = o1;
    }

    int lane = tid & 63, w = tid >> 6;
    int quad = lane >> 4, col0 = lane & 15;
    float bcv = bc2[w * 16 + col0];

    f16x8 bfr[8];
    #pragma unroll
    for (int kt = 0; kt < 8; ++kt)
        bfr[kt] = *reinterpret_cast<const f16x8*>(b2frag + ((size_t)(kt * 4 + w) * 64 + lane) * 8);

    __syncthreads();

    f32x4 acc = (f32x4){0.f, 0.f, 0.f, 0.f};
    #pragma unroll
    for (int kt = 0; kt < 8; ++kt) {
        f16x8 a = *reinterpret_cast<const f16x8*>(&cat[col0][kt * 32 + quad * 8]);
        acc = __builtin_amdgcn_mfma_f32_16x16x32_f16(a, bfr[kt], acc, 0, 0, 0);
    }

    int row0 = blockIdx.x * 16 + quad * 4;
    #pragma unroll
    for (int i = 0; i < 4; ++i)
        out[(size_t)(row0 + i) * 64 + w * 16 + col0] = fmaxf(acc[i] + bcv, 0.f);
}

// ---------------- launch ----------------
extern "C" void kernel_launch(void* const* d_in, const int* in_sizes, int n_in,
                              void* d_out, int out_size, void* d_ws, size_t ws_size,
                              hipStream_t stream)
{
    const float* x = (const float*)d_in[0];
    EPtrs ep;
    for (int i = 0; i < 9; ++i) { const int* p = (const int*)d_in[1 + i]; ep.s[i] = p; ep.d[i] = p + NE; }
    const float* W0n = (const float*)d_in[10]; const float* W0r = (const float*)d_in[11];
    const float* b0  = (const float*)d_in[12];
    const float* W1n = (const float*)d_in[13]; const float* W1r = (const float*)d_in[14];
    const float* b1  = (const float*)d_in[15];
    const float* P1  = (const float*)d_in[16]; const float* pb1 = (const float*)d_in[17];
    const float* W2n = (const float*)d_in[18]; const float* W2r = (const float*)d_in[19];
    const float* b2  = (const float*)d_in[20];
    const float* P2  = (const float*)d_in[21]; const float* pb2 = (const float*)d_in[22];
    float* out = (float*)d_out;
    char* ws = (char*)d_ws;

    size_t off_b = 0;
    auto alloc = [&](size_t b) { size_t o = off_b; off_b += (b + 255) & ~(size_t)255; return o; };
    size_t o_wc0 = alloc(288 * 4);   size_t o_bc0 = alloc(16 * 4);
    size_t o_wc1 = alloc(1536 * 4);  size_t o_bc1 = alloc(32 * 4);
    size_t o_b2f = alloc(16384 * 2); size_t o_bc2 = alloc(64 * 4);
    size_t o_h0h = alloc((size_t)NN * 16 * 2);
    size_t o_h1q = alloc((size_t)NN * 32);             // fp8 e4m3 gather table (3.2 MB)
    size_t o_h1h = alloc((size_t)NN * 32 * 2);         // compact h1 f16 (6.4 MB)
    size_t o_bin = alloc((size_t)NBIN * CAP * 4);      // 37.7 MB
    size_t o_deg = alloc((size_t)9 * NN * 4);
    size_t o_off = alloc((size_t)9 * NN * 4);
    size_t o_eid = alloc((size_t)NBIN * CAP * 4);      // 37.7 MB
    size_t o_cur = alloc((size_t)NBIN * 4);
    (void)ws_size;  // ~96 MB total

    float* wc0 = (float*)(ws + o_wc0); float* bc0 = (float*)(ws + o_bc0);
    float* wc1 = (float*)(ws + o_wc1); float* bc1 = (float*)(ws + o_bc1);
    f16*   b2f = (f16*)(ws + o_b2f);   float* bc2 = (float*)(ws + o_bc2);
    f16*   h0h = (f16*)(ws + o_h0h);
    unsigned* h1q = (unsigned*)(ws + o_h1q);
    f16*   h1h = (f16*)(ws + o_h1h);
    unsigned* binbuf = (unsigned*)(ws + o_bin);
    int*   deg = (int*)(ws + o_deg);
    int*   offp = (int*)(ws + o_off);
    int*   eid = (int*)(ws + o_eid);
    int*   cur = (int*)(ws + o_cur);

    dim3 B(256);
    prep_weights<<<32, B, 0, stream>>>(W0n, W0r, b0, W1n, W1r, b1, P1, pb1,
                                       W2n, W2r, b2, P2, pb2,
                                       wc0, bc0, wc1, bc1, b2f, bc2, cur);
    passA<<<dim3((NE + ACH - 1) / ACH, 9), dim3(ABD), 0, stream>>>(ep, cur, binbuf);
    passB<<<NBIN, B, 0, stream>>>(binbuf, cur, deg, offp, eid);

    t0f<<<(NN * 4 + 255) / 256, B, 0, stream>>>(x, deg, offp, eid, wc0, bc0, h0h);
    g1t<<<(NN + 31) / 32, B, 0, stream>>>(deg, offp, eid, h0h, wc1, bc1, h1h, h1q);
    g2t2<<<NN / 16, B, 0, stream>>>(deg, offp, eid, h1q, h1h, b2f, bc2, out);
}